// Round 1
// baseline (2154.654 us; speedup 1.0000x reference)
//
#include <hip/hip_runtime.h>

#define TPB 256
#define BT  64

// ---------------------------------------------------------------------------
// Kernel A: per-triple MLP, fused gather + GEMM1(384->128) + GEMM2(128->384)
// + scatter-add into pooled (d_out new_obj region) + counts + new_p store.
// block = 256 threads, 64 triples per block. Each thread owns an 8x4 output
// sub-tile (rows ty*8+i, cols tx*4+j).
// ---------------------------------------------------------------------------
__global__ __launch_bounds__(TPB, 2) void triple_mlp_kernel(
    const float* __restrict__ obj, const float* __restrict__ predi,
    const int* __restrict__ edges,
    const float* __restrict__ w1a, const float* __restrict__ b1a,
    const float* __restrict__ w1b, const float* __restrict__ b1b,
    float* __restrict__ pooled, float* __restrict__ out_p,
    float* __restrict__ counts, int T)
{
    __shared__ int   sIdx[BT];
    __shared__ int   oIdx[BT];
    __shared__ float Xs[BT][32];
    __shared__ float Ws[32][128];
    __shared__ float Hs[BT][128];

    const int tid = threadIdx.x;
    const int t0  = blockIdx.x * BT;
    const int ty  = tid >> 5;
    const int tx  = tid & 31;

    if (tid < BT) {
        int t  = t0 + tid;
        int tc = (t < T) ? t : (T - 1);
        sIdx[tid] = edges[2 * tc + 0];
        oIdx[tid] = edges[2 * tc + 1];
    }
    __syncthreads();

    // counts scatter (one atomic per endpoint per triple)
    if (tid < BT) {
        if (t0 + tid < T) atomicAdd(&counts[sIdx[tid]], 1.0f);
    } else if (tid < 2 * BT) {
        int r = tid - BT;
        if (t0 + r < T) atomicAdd(&counts[oIdx[r]], 1.0f);
    }

    float acc[8][4];
#pragma unroll
    for (int i = 0; i < 8; ++i)
#pragma unroll
        for (int j = 0; j < 4; ++j) acc[i][j] = 0.0f;

    // ---- GEMM1: X(64x384) @ w1a(384x128) ----
    for (int kc = 0; kc < 12; ++kc) {
        __syncthreads();
        // stage Xs (64x32): 512 float4, 2 per thread (gathered rows)
        const int seg = kc >> 2;          // 0: obj[s], 1: predi, 2: obj[o]
        const int k0  = (kc & 3) * 32;    // offset within segment
#pragma unroll
        for (int m = 0; m < 2; ++m) {
            int q   = tid * 2 + m;        // 0..511
            int row = q >> 3;
            int c4  = (q & 7) * 4;
            int t   = t0 + row;
            int tc  = (t < T) ? t : (T - 1);
            const float* src;
            if (seg == 0)      src = obj   + (size_t)sIdx[row] * 128 + k0 + c4;
            else if (seg == 1) src = predi + (size_t)tc        * 128 + k0 + c4;
            else               src = obj   + (size_t)oIdx[row] * 128 + k0 + c4;
            *(float4*)&Xs[row][c4] = *(const float4*)src;
        }
        // stage Ws (32x128): 1024 float4, 4 per thread
#pragma unroll
        for (int m = 0; m < 4; ++m) {
            int q  = m * 256 + tid;       // 0..1023
            int kk = q >> 5;
            int c4 = (q & 31) * 4;
            *(float4*)&Ws[kk][c4] =
                *(const float4*)&w1a[(size_t)(kc * 32 + kk) * 128 + c4];
        }
        __syncthreads();
#pragma unroll
        for (int k4 = 0; k4 < 32; k4 += 4) {
            float4 xr[8];
#pragma unroll
            for (int i = 0; i < 8; ++i)
                xr[i] = *(const float4*)&Xs[ty * 8 + i][k4];
#pragma unroll
            for (int u = 0; u < 4; ++u) {
                float4 wv = *(const float4*)&Ws[k4 + u][tx * 4];
#pragma unroll
                for (int i = 0; i < 8; ++i) {
                    float x = ((const float*)&xr[i])[u];
                    acc[i][0] = fmaf(x, wv.x, acc[i][0]);
                    acc[i][1] = fmaf(x, wv.y, acc[i][1]);
                    acc[i][2] = fmaf(x, wv.z, acc[i][2]);
                    acc[i][3] = fmaf(x, wv.w, acc[i][3]);
                }
            }
        }
    }

    // bias + relu -> Hs
    {
        float4 bb = *(const float4*)&b1a[tx * 4];
#pragma unroll
        for (int i = 0; i < 8; ++i) {
            float4 h;
            h.x = fmaxf(acc[i][0] + bb.x, 0.0f);
            h.y = fmaxf(acc[i][1] + bb.y, 0.0f);
            h.z = fmaxf(acc[i][2] + bb.z, 0.0f);
            h.w = fmaxf(acc[i][3] + bb.w, 0.0f);
            *(float4*)&Hs[ty * 8 + i][tx * 4] = h;
        }
    }

    // ---- GEMM2: H(64x128) @ w1b(128x384), 3 col-chunks of 128 ----
    for (int chunk = 0; chunk < 3; ++chunk) {
        float a2[8][4];
#pragma unroll
        for (int i = 0; i < 8; ++i)
#pragma unroll
            for (int j = 0; j < 4; ++j) a2[i][j] = 0.0f;

        for (int kc = 0; kc < 4; ++kc) {
            __syncthreads();   // prev Ws use (and Hs writes on first iter) done
#pragma unroll
            for (int m = 0; m < 4; ++m) {
                int q  = m * 256 + tid;
                int kk = q >> 5;
                int c4 = (q & 31) * 4;
                *(float4*)&Ws[kk][c4] =
                    *(const float4*)&w1b[(size_t)(kc * 32 + kk) * 384 + chunk * 128 + c4];
            }
            __syncthreads();
#pragma unroll
            for (int k4 = 0; k4 < 32; k4 += 4) {
                float4 xr[8];
#pragma unroll
                for (int i = 0; i < 8; ++i)
                    xr[i] = *(const float4*)&Hs[ty * 8 + i][kc * 32 + k4];
#pragma unroll
                for (int u = 0; u < 4; ++u) {
                    float4 wv = *(const float4*)&Ws[k4 + u][tx * 4];
#pragma unroll
                    for (int i = 0; i < 8; ++i) {
                        float x = ((const float*)&xr[i])[u];
                        a2[i][0] = fmaf(x, wv.x, a2[i][0]);
                        a2[i][1] = fmaf(x, wv.y, a2[i][1]);
                        a2[i][2] = fmaf(x, wv.z, a2[i][2]);
                        a2[i][3] = fmaf(x, wv.w, a2[i][3]);
                    }
                }
            }
        }

        float4 bb = *(const float4*)&b1b[chunk * 128 + tx * 4];
#pragma unroll
        for (int i = 0; i < 8; ++i) {
            int r = ty * 8 + i;
            if (t0 + r >= T) continue;
            float v0 = fmaxf(a2[i][0] + bb.x, 0.0f);
            float v1 = fmaxf(a2[i][1] + bb.y, 0.0f);
            float v2 = fmaxf(a2[i][2] + bb.z, 0.0f);
            float v3 = fmaxf(a2[i][3] + bb.w, 0.0f);
            if (chunk == 1) {
                float4 o = make_float4(v0, v1, v2, v3);
                *(float4*)&out_p[(size_t)(t0 + r) * 128 + tx * 4] = o;
            } else {
                int idx = (chunk == 0) ? sIdx[r] : oIdx[r];
                float* dst = pooled + (size_t)idx * 128 + tx * 4;
                atomicAdd(dst + 0, v0);
                atomicAdd(dst + 1, v1);
                atomicAdd(dst + 2, v2);
                atomicAdd(dst + 3, v3);
            }
        }
    }
}

// ---------------------------------------------------------------------------
// Kernel C: object MLP. Loads pooled rows (divided by clipped counts) into
// LDS, computes relu(relu(p@w2a+b2a)@w2b+b2b), writes new_obj in-place.
// ---------------------------------------------------------------------------
__global__ __launch_bounds__(TPB, 2) void obj_mlp_kernel(
    const float* __restrict__ w2a, const float* __restrict__ b2a,
    const float* __restrict__ w2b, const float* __restrict__ b2b,
    float* __restrict__ pooled_out, const float* __restrict__ counts, int O)
{
    __shared__ float Ps[BT][128];
    __shared__ float Ws[32][128];

    const int tid = threadIdx.x;
    const int ty  = tid >> 5;
    const int tx  = tid & 31;
    const int r0  = blockIdx.x * BT;

    // stage Ps = pooled / clamp(counts, 1, 1000)
#pragma unroll
    for (int m = 0; m < 8; ++m) {
        int q   = m * 256 + tid;      // 0..2047
        int row = q >> 5;
        int c4  = (q & 31) * 4;
        int rg  = r0 + row;
        if (rg > O - 1) rg = O - 1;
        float c = counts[rg];
        c = fminf(fmaxf(c, 1.0f), 1000.0f);
        float inv = 1.0f / c;
        float4 v = *(const float4*)&pooled_out[(size_t)rg * 128 + c4];
        v.x *= inv; v.y *= inv; v.z *= inv; v.w *= inv;
        *(float4*)&Ps[row][c4] = v;
    }

    float acc[8][4];
#pragma unroll
    for (int i = 0; i < 8; ++i)
#pragma unroll
        for (int j = 0; j < 4; ++j) acc[i][j] = 0.0f;

    // GEMM1: Ps @ w2a (128x128)
    for (int kc = 0; kc < 4; ++kc) {
        __syncthreads();
#pragma unroll
        for (int m = 0; m < 4; ++m) {
            int q  = m * 256 + tid;
            int kk = q >> 5;
            int c4 = (q & 31) * 4;
            *(float4*)&Ws[kk][c4] =
                *(const float4*)&w2a[(size_t)(kc * 32 + kk) * 128 + c4];
        }
        __syncthreads();
#pragma unroll
        for (int k4 = 0; k4 < 32; k4 += 4) {
            float4 xr[8];
#pragma unroll
            for (int i = 0; i < 8; ++i)
                xr[i] = *(const float4*)&Ps[ty * 8 + i][kc * 32 + k4];
#pragma unroll
            for (int u = 0; u < 4; ++u) {
                float4 wv = *(const float4*)&Ws[k4 + u][tx * 4];
#pragma unroll
                for (int i = 0; i < 8; ++i) {
                    float x = ((const float*)&xr[i])[u];
                    acc[i][0] = fmaf(x, wv.x, acc[i][0]);
                    acc[i][1] = fmaf(x, wv.y, acc[i][1]);
                    acc[i][2] = fmaf(x, wv.z, acc[i][2]);
                    acc[i][3] = fmaf(x, wv.w, acc[i][3]);
                }
            }
        }
    }

    // h = relu(acc + b2a) -> back into Ps (all reads done after sync)
    __syncthreads();
    {
        float4 bb = *(const float4*)&b2a[tx * 4];
#pragma unroll
        for (int i = 0; i < 8; ++i) {
            float4 h;
            h.x = fmaxf(acc[i][0] + bb.x, 0.0f);
            h.y = fmaxf(acc[i][1] + bb.y, 0.0f);
            h.z = fmaxf(acc[i][2] + bb.z, 0.0f);
            h.w = fmaxf(acc[i][3] + bb.w, 0.0f);
            *(float4*)&Ps[ty * 8 + i][tx * 4] = h;
        }
    }

    float a2[8][4];
#pragma unroll
    for (int i = 0; i < 8; ++i)
#pragma unroll
        for (int j = 0; j < 4; ++j) a2[i][j] = 0.0f;

    // GEMM2: h @ w2b (128x128)
    for (int kc = 0; kc < 4; ++kc) {
        __syncthreads();
#pragma unroll
        for (int m = 0; m < 4; ++m) {
            int q  = m * 256 + tid;
            int kk = q >> 5;
            int c4 = (q & 31) * 4;
            *(float4*)&Ws[kk][c4] =
                *(const float4*)&w2b[(size_t)(kc * 32 + kk) * 128 + c4];
        }
        __syncthreads();
#pragma unroll
        for (int k4 = 0; k4 < 32; k4 += 4) {
            float4 xr[8];
#pragma unroll
            for (int i = 0; i < 8; ++i)
                xr[i] = *(const float4*)&Ps[ty * 8 + i][kc * 32 + k4];
#pragma unroll
            for (int u = 0; u < 4; ++u) {
                float4 wv = *(const float4*)&Ws[k4 + u][tx * 4];
#pragma unroll
                for (int i = 0; i < 8; ++i) {
                    float x = ((const float*)&xr[i])[u];
                    a2[i][0] = fmaf(x, wv.x, a2[i][0]);
                    a2[i][1] = fmaf(x, wv.y, a2[i][1]);
                    a2[i][2] = fmaf(x, wv.z, a2[i][2]);
                    a2[i][3] = fmaf(x, wv.w, a2[i][3]);
                }
            }
        }
    }

    {
        float4 bb = *(const float4*)&b2b[tx * 4];
#pragma unroll
        for (int i = 0; i < 8; ++i) {
            int r = ty * 8 + i;
            if (r0 + r >= O) continue;
            float4 o;
            o.x = fmaxf(a2[i][0] + bb.x, 0.0f);
            o.y = fmaxf(a2[i][1] + bb.y, 0.0f);
            o.z = fmaxf(a2[i][2] + bb.z, 0.0f);
            o.w = fmaxf(a2[i][3] + bb.w, 0.0f);
            *(float4*)&pooled_out[(size_t)(r0 + r) * 128 + tx * 4] = o;
        }
    }
}

extern "C" void kernel_launch(void* const* d_in, const int* in_sizes, int n_in,
                              void* d_out, int out_size, void* d_ws, size_t ws_size,
                              hipStream_t stream) {
    const float* obj   = (const float*)d_in[0];
    const float* predi = (const float*)d_in[1];
    const int*   edges = (const int*)d_in[2];
    const float* w1a   = (const float*)d_in[3];
    const float* b1a   = (const float*)d_in[4];
    const float* w1b   = (const float*)d_in[5];
    const float* b1b   = (const float*)d_in[6];
    const float* w2a   = (const float*)d_in[7];
    const float* b2a   = (const float*)d_in[8];
    const float* w2b   = (const float*)d_in[9];
    const float* b2b   = (const float*)d_in[10];

    const int O = in_sizes[0] / 128;
    const int T = in_sizes[1] / 128;

    float* out    = (float*)d_out;
    float* pooled = out;                       // new_obj region doubles as pooled scratch
    float* out_p  = out + (size_t)O * 128;     // new_p region
    float* counts = (float*)d_ws;              // O floats

    hipMemsetAsync(pooled, 0, (size_t)O * 128 * sizeof(float), stream);
    hipMemsetAsync(counts, 0, (size_t)O * sizeof(float), stream);

    const int gridA = (T + BT - 1) / BT;
    triple_mlp_kernel<<<gridA, TPB, 0, stream>>>(
        obj, predi, edges, w1a, b1a, w1b, b1b, pooled, out_p, counts, T);

    const int gridC = (O + BT - 1) / BT;
    obj_mlp_kernel<<<gridC, TPB, 0, stream>>>(
        w2a, b2a, w2b, b2b, pooled, counts, O);
}

// Round 2
// 1185.529 us; speedup vs baseline: 1.8175x; 1.8175x over previous
//
#include <hip/hip_runtime.h>

typedef __attribute__((ext_vector_type(8))) short bf16x8;
typedef __attribute__((ext_vector_type(4))) float f32x4;
typedef __attribute__((ext_vector_type(4))) unsigned short u16x4;

#define MFMA __builtin_amdgcn_mfma_f32_16x16x32_bf16

__device__ __forceinline__ unsigned short f2bf(float x) {
    union { float f; unsigned u; } v; v.f = x;
    unsigned r = v.u + 0x7FFFu + ((v.u >> 16) & 1u);
    return (unsigned short)(r >> 16);
}
__device__ __forceinline__ float bf2f(unsigned short h) {
    union { unsigned u; float f; } v; v.u = ((unsigned)h) << 16;
    return v.f;
}

// ---------------------------------------------------------------------------
// Pack weights into MFMA B-fragment layout, bf16 hi/lo split.
// Tile = 32(K) x 16(N). Lane l of a tile holds B[kc*32+(l>>4)*8+j][ct*16+(l&15)],
// j=0..7, stored contiguously: pk[(tile*64+l)*8 + j]. Tiles ordered [kc][ct].
// Regions (shorts): pk1a_h(96*512) pk1a_l pk1b_h pk1b_l pk2a_h(32*512) pk2a_l pk2b_h pk2b_l
// ---------------------------------------------------------------------------
__global__ void pack_weights(const float* __restrict__ w1a, const float* __restrict__ w1b,
                             const float* __restrict__ w2a, const float* __restrict__ w2b,
                             unsigned short* __restrict__ pk)
{
    const int b = blockIdx.x, l = threadIdx.x;
    const float* W; int N, tile; unsigned short *ph, *pl;
    if (b < 96)       { W = w1a; N = 128; tile = b;       ph = pk;                 pl = pk + 96*512; }
    else if (b < 192) { W = w1b; N = 384; tile = b - 96;  ph = pk + 2*96*512;      pl = pk + 3*96*512; }
    else if (b < 224) { W = w2a; N = 128; tile = b - 192; ph = pk + 4*96*512;      pl = pk + 4*96*512 + 32*512; }
    else              { W = w2b; N = 128; tile = b - 224; ph = pk + 4*96*512 + 2*32*512; pl = pk + 4*96*512 + 3*32*512; }
    const int tpr = N / 16;
    const int kc = tile / tpr, ct = tile % tpr;
    bf16x8 hv, lv;
#pragma unroll
    for (int j = 0; j < 8; ++j) {
        int k = kc * 32 + (l >> 4) * 8 + j;
        int n = ct * 16 + (l & 15);
        float v = W[(size_t)k * N + n];
        unsigned short h = f2bf(v);
        hv[j] = (short)h;
        lv[j] = (short)f2bf(v - bf2f(h));
    }
    *(bf16x8*)&ph[(size_t)(tile * 64 + l) * 8] = hv;
    *(bf16x8*)&pl[(size_t)(tile * 64 + l) * 8] = lv;
}

// ---------------------------------------------------------------------------
// Kernel A: per-triple MLP with MFMA (hi/lo bf16 split, 3 passes).
// Block = 256 thr = 4 waves, 64 triples. GEMM1: wave w owns cols [32w,32w+32)
// of 128; GEMM2: wave w owns cols [96w,96w+96) of 384.
// X/H staged in LDS bf16 hi/lo with XOR swizzle (shorts: col ^ ((row&7)<<3)).
// ---------------------------------------------------------------------------
__global__ __launch_bounds__(256) void triple_mlp_mfma(
    const float* __restrict__ obj, const float* __restrict__ predi,
    const int* __restrict__ edges,
    const float* __restrict__ b1a, const float* __restrict__ b1b,
    const unsigned short* __restrict__ pk1a_h, const unsigned short* __restrict__ pk1a_l,
    const unsigned short* __restrict__ pk1b_h, const unsigned short* __restrict__ pk1b_l,
    float* __restrict__ pooled, float* __restrict__ out_p,
    float* __restrict__ counts, int T)
{
    __shared__ __align__(16) unsigned short Xh[64 * 128];
    __shared__ __align__(16) unsigned short Xl[64 * 128];
    __shared__ int sIdx[64], oIdx[64];

    const int tid = threadIdx.x;
    const int w = tid >> 6, l = tid & 63;
    const int t0 = blockIdx.x * 64;

    if (tid < 64) {
        int t = t0 + tid; int tc = (t < T) ? t : (T - 1);
        sIdx[tid] = edges[2 * tc];
        oIdx[tid] = edges[2 * tc + 1];
    }
    __syncthreads();

    if (tid < 64)        { if (t0 + tid      < T) atomicAdd(&counts[sIdx[tid]],      1.0f); }
    else if (tid < 128)  { if (t0 + tid - 64 < T) atomicAdd(&counts[oIdx[tid - 64]], 1.0f); }

    f32x4 acc1[4][2];
#pragma unroll
    for (int i = 0; i < 4; ++i) { acc1[i][0] = (f32x4)0.0f; acc1[i][1] = (f32x4)0.0f; }

    // ---- GEMM1: X(64x384) @ w1a, K in 3 segments of 128 ----
#pragma unroll
    for (int s = 0; s < 3; ++s) {
        // stage segment: 64x128 f32 -> bf16 hi/lo, swizzled
#pragma unroll
        for (int it = 0; it < 8; ++it) {
            int q = it * 256 + tid;
            int row = q >> 5, c4 = (q & 31) * 4;
            int t = t0 + row; int tc = (t < T) ? t : (T - 1);
            const float* src = (s == 0) ? obj   + (size_t)sIdx[row] * 128 + c4
                             : (s == 1) ? predi + (size_t)tc        * 128 + c4
                                        : obj   + (size_t)oIdx[row] * 128 + c4;
            float4 v = *(const float4*)src;
            u16x4 hv, lv;
            unsigned short h;
            h = f2bf(v.x); hv[0] = h; lv[0] = f2bf(v.x - bf2f(h));
            h = f2bf(v.y); hv[1] = h; lv[1] = f2bf(v.y - bf2f(h));
            h = f2bf(v.z); hv[2] = h; lv[2] = f2bf(v.z - bf2f(h));
            h = f2bf(v.w); hv[3] = h; lv[3] = f2bf(v.w - bf2f(h));
            int pc = row * 128 + (c4 ^ ((row & 7) << 3));
            *(u16x4*)&Xh[pc] = hv;
            *(u16x4*)&Xl[pc] = lv;
        }
        __syncthreads();

#pragma unroll
        for (int kc2 = 0; kc2 < 4; ++kc2) {
            const int kcg = s * 4 + kc2;
            bf16x8 ah[4], al[4];
#pragma unroll
            for (int rt = 0; rt < 4; ++rt) {
                int row = rt * 16 + (l & 15);
                int col0 = kc2 * 32 + (l >> 4) * 8;
                int pc = row * 128 + (col0 ^ ((row & 7) << 3));
                ah[rt] = *(const bf16x8*)&Xh[pc];
                al[rt] = *(const bf16x8*)&Xl[pc];
            }
#pragma unroll
            for (int c2 = 0; c2 < 2; ++c2) {
                const int tile = kcg * 8 + w * 2 + c2;
                bf16x8 bh = *(const bf16x8*)&pk1a_h[(size_t)(tile * 64 + l) * 8];
                bf16x8 bl = *(const bf16x8*)&pk1a_l[(size_t)(tile * 64 + l) * 8];
#pragma unroll
                for (int rt = 0; rt < 4; ++rt) {
                    acc1[rt][c2] = MFMA(ah[rt], bh, acc1[rt][c2], 0, 0, 0);
                    acc1[rt][c2] = MFMA(ah[rt], bl, acc1[rt][c2], 0, 0, 0);
                    acc1[rt][c2] = MFMA(al[rt], bh, acc1[rt][c2], 0, 0, 0);
                }
            }
        }
        __syncthreads();   // before next segment restages Xh/Xl
    }

    // ---- H = relu(acc1 + b1a) -> Xh/Xl (hi/lo, swizzled) ----
#pragma unroll
    for (int c2 = 0; c2 < 2; ++c2) {
        int col = w * 32 + c2 * 16 + (l & 15);
        float bb = b1a[col];
#pragma unroll
        for (int rt = 0; rt < 4; ++rt) {
#pragma unroll
            for (int r = 0; r < 4; ++r) {
                int row = rt * 16 + (l >> 4) * 4 + r;
                float h = fmaxf(acc1[rt][c2][r] + bb, 0.0f);
                unsigned short hh = f2bf(h);
                unsigned short hl = f2bf(h - bf2f(hh));
                int pc = row * 128 + (col ^ ((row & 7) << 3));
                Xh[pc] = hh; Xl[pc] = hl;
            }
        }
    }
    __syncthreads();

    // ---- GEMM2: H(64x128) @ w1b(128x384) ----
    f32x4 acc2[4][6];
#pragma unroll
    for (int i = 0; i < 4; ++i)
#pragma unroll
        for (int j = 0; j < 6; ++j) acc2[i][j] = (f32x4)0.0f;

#pragma unroll
    for (int kc = 0; kc < 4; ++kc) {
        bf16x8 ah[4], al[4];
#pragma unroll
        for (int rt = 0; rt < 4; ++rt) {
            int row = rt * 16 + (l & 15);
            int col0 = kc * 32 + (l >> 4) * 8;
            int pc = row * 128 + (col0 ^ ((row & 7) << 3));
            ah[rt] = *(const bf16x8*)&Xh[pc];
            al[rt] = *(const bf16x8*)&Xl[pc];
        }
#pragma unroll
        for (int ct = 0; ct < 6; ++ct) {
            const int tile = kc * 24 + w * 6 + ct;
            bf16x8 bh = *(const bf16x8*)&pk1b_h[(size_t)(tile * 64 + l) * 8];
            bf16x8 bl = *(const bf16x8*)&pk1b_l[(size_t)(tile * 64 + l) * 8];
#pragma unroll
            for (int rt = 0; rt < 4; ++rt) {
                acc2[rt][ct] = MFMA(ah[rt], bh, acc2[rt][ct], 0, 0, 0);
                acc2[rt][ct] = MFMA(ah[rt], bl, acc2[rt][ct], 0, 0, 0);
                acc2[rt][ct] = MFMA(al[rt], bh, acc2[rt][ct], 0, 0, 0);
            }
        }
    }

    // ---- epilogue: relu(+b1b); cols 0-127 -> scatter s, 128-255 -> new_p, 256-383 -> scatter o
#pragma unroll
    for (int ct = 0; ct < 6; ++ct) {
        int col = w * 96 + ct * 16 + (l & 15);
        float bb = b1b[col];
#pragma unroll
        for (int rt = 0; rt < 4; ++rt) {
#pragma unroll
            for (int r = 0; r < 4; ++r) {
                int row = rt * 16 + (l >> 4) * 4 + r;
                if (t0 + row >= T) continue;
                float v = fmaxf(acc2[rt][ct][r] + bb, 0.0f);
                if (col < 128)
                    atomicAdd(&pooled[(size_t)sIdx[row] * 128 + col], v);
                else if (col < 256)
                    out_p[(size_t)(t0 + row) * 128 + (col - 128)] = v;
                else
                    atomicAdd(&pooled[(size_t)oIdx[row] * 128 + (col - 256)], v);
            }
        }
    }
}

// ---------------------------------------------------------------------------
// Kernel C: object MLP with MFMA. In-place over pooled region of d_out.
// ---------------------------------------------------------------------------
__global__ __launch_bounds__(256) void obj_mlp_mfma(
    const float* __restrict__ b2a, const float* __restrict__ b2b,
    const unsigned short* __restrict__ pk2a_h, const unsigned short* __restrict__ pk2a_l,
    const unsigned short* __restrict__ pk2b_h, const unsigned short* __restrict__ pk2b_l,
    float* __restrict__ io, const float* __restrict__ counts, int O)
{
    __shared__ __align__(16) unsigned short Xh[64 * 128];
    __shared__ __align__(16) unsigned short Xl[64 * 128];

    const int tid = threadIdx.x;
    const int w = tid >> 6, l = tid & 63;
    const int r0 = blockIdx.x * 64;

    // stage pooled/counts -> normalized x, bf16 hi/lo swizzled
#pragma unroll
    for (int it = 0; it < 8; ++it) {
        int q = it * 256 + tid;
        int row = q >> 5, c4 = (q & 31) * 4;
        int rg = r0 + row; if (rg > O - 1) rg = O - 1;
        float c = counts[rg];
        c = fminf(fmaxf(c, 1.0f), 1000.0f);
        float inv = 1.0f / c;
        float4 v = *(const float4*)&io[(size_t)rg * 128 + c4];
        v.x *= inv; v.y *= inv; v.z *= inv; v.w *= inv;
        u16x4 hv, lv;
        unsigned short h;
        h = f2bf(v.x); hv[0] = h; lv[0] = f2bf(v.x - bf2f(h));
        h = f2bf(v.y); hv[1] = h; lv[1] = f2bf(v.y - bf2f(h));
        h = f2bf(v.z); hv[2] = h; lv[2] = f2bf(v.z - bf2f(h));
        h = f2bf(v.w); hv[3] = h; lv[3] = f2bf(v.w - bf2f(h));
        int pc = row * 128 + (c4 ^ ((row & 7) << 3));
        *(u16x4*)&Xh[pc] = hv;
        *(u16x4*)&Xl[pc] = lv;
    }
    __syncthreads();

    f32x4 acc[4][2];
#pragma unroll
    for (int i = 0; i < 4; ++i) { acc[i][0] = (f32x4)0.0f; acc[i][1] = (f32x4)0.0f; }

    // GEMM1: x @ w2a (128x128)
#pragma unroll
    for (int kc = 0; kc < 4; ++kc) {
        bf16x8 ah[4], al[4];
#pragma unroll
        for (int rt = 0; rt < 4; ++rt) {
            int row = rt * 16 + (l & 15);
            int col0 = kc * 32 + (l >> 4) * 8;
            int pc = row * 128 + (col0 ^ ((row & 7) << 3));
            ah[rt] = *(const bf16x8*)&Xh[pc];
            al[rt] = *(const bf16x8*)&Xl[pc];
        }
#pragma unroll
        for (int c2 = 0; c2 < 2; ++c2) {
            const int tile = kc * 8 + w * 2 + c2;
            bf16x8 bh = *(const bf16x8*)&pk2a_h[(size_t)(tile * 64 + l) * 8];
            bf16x8 bl = *(const bf16x8*)&pk2a_l[(size_t)(tile * 64 + l) * 8];
#pragma unroll
            for (int rt = 0; rt < 4; ++rt) {
                acc[rt][c2] = MFMA(ah[rt], bh, acc[rt][c2], 0, 0, 0);
                acc[rt][c2] = MFMA(ah[rt], bl, acc[rt][c2], 0, 0, 0);
                acc[rt][c2] = MFMA(al[rt], bh, acc[rt][c2], 0, 0, 0);
            }
        }
    }
    __syncthreads();   // all GEMM1 reads done before H overwrite

    // H = relu(acc + b2a) -> Xh/Xl
#pragma unroll
    for (int c2 = 0; c2 < 2; ++c2) {
        int col = w * 32 + c2 * 16 + (l & 15);
        float bb = b2a[col];
#pragma unroll
        for (int rt = 0; rt < 4; ++rt) {
#pragma unroll
            for (int r = 0; r < 4; ++r) {
                int row = rt * 16 + (l >> 4) * 4 + r;
                float h = fmaxf(acc[rt][c2][r] + bb, 0.0f);
                unsigned short hh = f2bf(h);
                unsigned short hl = f2bf(h - bf2f(hh));
                int pc = row * 128 + (col ^ ((row & 7) << 3));
                Xh[pc] = hh; Xl[pc] = hl;
            }
        }
    }
    __syncthreads();

    f32x4 acc2[4][2];
#pragma unroll
    for (int i = 0; i < 4; ++i) { acc2[i][0] = (f32x4)0.0f; acc2[i][1] = (f32x4)0.0f; }

    // GEMM2: h @ w2b (128x128)
#pragma unroll
    for (int kc = 0; kc < 4; ++kc) {
        bf16x8 ah[4], al[4];
#pragma unroll
        for (int rt = 0; rt < 4; ++rt) {
            int row = rt * 16 + (l & 15);
            int col0 = kc * 32 + (l >> 4) * 8;
            int pc = row * 128 + (col0 ^ ((row & 7) << 3));
            ah[rt] = *(const bf16x8*)&Xh[pc];
            al[rt] = *(const bf16x8*)&Xl[pc];
        }
#pragma unroll
        for (int c2 = 0; c2 < 2; ++c2) {
            const int tile = kc * 8 + w * 2 + c2;
            bf16x8 bh = *(const bf16x8*)&pk2b_h[(size_t)(tile * 64 + l) * 8];
            bf16x8 bl = *(const bf16x8*)&pk2b_l[(size_t)(tile * 64 + l) * 8];
#pragma unroll
            for (int rt = 0; rt < 4; ++rt) {
                acc2[rt][c2] = MFMA(ah[rt], bh, acc2[rt][c2], 0, 0, 0);
                acc2[rt][c2] = MFMA(ah[rt], bl, acc2[rt][c2], 0, 0, 0);
                acc2[rt][c2] = MFMA(al[rt], bh, acc2[rt][c2], 0, 0, 0);
            }
        }
    }

    // epilogue: new_obj = relu(acc2 + b2b), in-place store
#pragma unroll
    for (int c2 = 0; c2 < 2; ++c2) {
        int col = w * 32 + c2 * 16 + (l & 15);
        float bb = b2b[col];
#pragma unroll
        for (int rt = 0; rt < 4; ++rt) {
#pragma unroll
            for (int r = 0; r < 4; ++r) {
                int row = rt * 16 + (l >> 4) * 4 + r;
                if (r0 + row >= O) continue;
                float v = fmaxf(acc2[rt][c2][r] + bb, 0.0f);
                io[(size_t)(r0 + row) * 128 + col] = v;
            }
        }
    }
}

extern "C" void kernel_launch(void* const* d_in, const int* in_sizes, int n_in,
                              void* d_out, int out_size, void* d_ws, size_t ws_size,
                              hipStream_t stream) {
    const float* obj   = (const float*)d_in[0];
    const float* predi = (const float*)d_in[1];
    const int*   edges = (const int*)d_in[2];
    const float* w1a   = (const float*)d_in[3];
    const float* b1a   = (const float*)d_in[4];
    const float* w1b   = (const float*)d_in[5];
    const float* b1b   = (const float*)d_in[6];
    const float* w2a   = (const float*)d_in[7];
    const float* b2a   = (const float*)d_in[8];
    const float* w2b   = (const float*)d_in[9];
    const float* b2b   = (const float*)d_in[10];
    (void)n_in; (void)ws_size; (void)out_size;

    const int O = in_sizes[0] / 128;
    const int T = in_sizes[1] / 128;

    float* out    = (float*)d_out;
    float* pooled = out;                        // new_obj region doubles as pooled scratch
    float* out_p  = out + (size_t)O * 128;      // new_p region
    float* counts = (float*)d_ws;               // O floats

    unsigned short* pk = (unsigned short*)(counts + O);
    unsigned short* pk1a_h = pk;
    unsigned short* pk1a_l = pk1a_h + 96 * 512;
    unsigned short* pk1b_h = pk1a_l + 96 * 512;
    unsigned short* pk1b_l = pk1b_h + 96 * 512;
    unsigned short* pk2a_h = pk1b_l + 96 * 512;
    unsigned short* pk2a_l = pk2a_h + 32 * 512;
    unsigned short* pk2b_h = pk2a_l + 32 * 512;
    unsigned short* pk2b_l = pk2b_h + 32 * 512;

    hipMemsetAsync(pooled, 0, (size_t)O * 128 * sizeof(float), stream);
    hipMemsetAsync(counts, 0, (size_t)O * sizeof(float), stream);

    pack_weights<<<256, 64, 0, stream>>>(w1a, w1b, w2a, w2b, pk);

    triple_mlp_mfma<<<(T + 63) / 64, 256, 0, stream>>>(
        obj, predi, edges, b1a, b1b,
        pk1a_h, pk1a_l, pk1b_h, pk1b_l,
        pooled, out_p, counts, T);

    obj_mlp_mfma<<<(O + 63) / 64, 256, 0, stream>>>(
        b2a, b2b, pk2a_h, pk2a_l, pk2b_h, pk2b_l,
        pooled, counts, O);
}

// Round 3
// 983.953 us; speedup vs baseline: 2.1898x; 1.2049x over previous
//
#include <hip/hip_runtime.h>

typedef __attribute__((ext_vector_type(8))) short bf16x8;
typedef __attribute__((ext_vector_type(4))) float f32x4;
typedef __attribute__((ext_vector_type(4))) unsigned short u16x4;

#define MFMA __builtin_amdgcn_mfma_f32_16x16x32_bf16

__device__ __forceinline__ unsigned short f2bf(float x) {
    union { float f; unsigned u; } v; v.f = x;
    unsigned r = v.u + 0x7FFFu + ((v.u >> 16) & 1u);
    return (unsigned short)(r >> 16);
}
__device__ __forceinline__ float bf2f(unsigned short h) {
    union { unsigned u; float f; } v; v.u = ((unsigned)h) << 16;
    return v.f;
}

// ---------------------------------------------------------------------------
// Pack weights into MFMA B-fragment layout, bf16 hi/lo split.
// Tile = 32(K) x 16(N). Lane l holds B[kc*32+(l>>4)*8+j][ct*16+(l&15)], j=0..7,
// at pk[(tile*64+l)*8+j]. Tiles ordered [kc][ct].
// ---------------------------------------------------------------------------
__global__ void pack_weights(const float* __restrict__ w1a, const float* __restrict__ w1b,
                             const float* __restrict__ w2a, const float* __restrict__ w2b,
                             unsigned short* __restrict__ pk)
{
    const int b = blockIdx.x, l = threadIdx.x;
    const float* W; int N, tile; unsigned short *ph, *pl;
    if (b < 96)       { W = w1a; N = 128; tile = b;       ph = pk;                 pl = pk + 96*512; }
    else if (b < 192) { W = w1b; N = 384; tile = b - 96;  ph = pk + 2*96*512;      pl = pk + 3*96*512; }
    else if (b < 224) { W = w2a; N = 128; tile = b - 192; ph = pk + 4*96*512;      pl = pk + 4*96*512 + 32*512; }
    else              { W = w2b; N = 128; tile = b - 224; ph = pk + 4*96*512 + 2*32*512; pl = pk + 4*96*512 + 3*32*512; }
    const int tpr = N / 16;
    const int kc = tile / tpr, ct = tile % tpr;
    bf16x8 hv, lv;
#pragma unroll
    for (int j = 0; j < 8; ++j) {
        int k = kc * 32 + (l >> 4) * 8 + j;
        int n = ct * 16 + (l & 15);
        float v = W[(size_t)k * N + n];
        unsigned short h = f2bf(v);
        hv[j] = (short)h;
        lv[j] = (short)f2bf(v - bf2f(h));
    }
    *(bf16x8*)&ph[(size_t)(tile * 64 + l) * 8] = hv;
    *(bf16x8*)&pl[(size_t)(tile * 64 + l) * 8] = lv;
}

// ---------------------------------------------------------------------------
// Kernel A: per-triple MLP, MFMA hi/lo bf16 (3 passes). 512 thr = 8 waves,
// 64 triples/block. Wave w: row-half rh=(w&1) (rows 32rh..32rh+31),
// col group cg=(w>>1): GEMM1 cols [32cg,32cg+32), GEMM2 cols [96cg,96cg+96).
// acc1[2][2]=16 regs, acc2[2][6]=48 regs -> ~100 VGPR peak -> 2 blocks/CU.
// ---------------------------------------------------------------------------
__global__ __launch_bounds__(512, 4) void triple_mlp_mfma(
    const float* __restrict__ obj, const float* __restrict__ predi,
    const int* __restrict__ edges,
    const float* __restrict__ b1a, const float* __restrict__ b1b,
    const unsigned short* __restrict__ pk1a_h, const unsigned short* __restrict__ pk1a_l,
    const unsigned short* __restrict__ pk1b_h, const unsigned short* __restrict__ pk1b_l,
    float* __restrict__ pooled, float* __restrict__ out_p,
    float* __restrict__ counts, int T)
{
    __shared__ __align__(16) unsigned short Xh[64 * 128];
    __shared__ __align__(16) unsigned short Xl[64 * 128];
    __shared__ int sIdx[64], oIdx[64];

    const int tid = threadIdx.x;
    const int w = tid >> 6, l = tid & 63;
    const int rh = w & 1, cg = w >> 1;
    const int t0 = blockIdx.x * 64;

    if (tid < 64) {
        int t = t0 + tid; int tc = (t < T) ? t : (T - 1);
        sIdx[tid] = edges[2 * tc];
        oIdx[tid] = edges[2 * tc + 1];
    }
    __syncthreads();

    if (tid < 64)        { if (t0 + tid      < T) atomicAdd(&counts[sIdx[tid]],      1.0f); }
    else if (tid < 128)  { if (t0 + tid - 64 < T) atomicAdd(&counts[oIdx[tid - 64]], 1.0f); }

    f32x4 acc1[2][2];
#pragma unroll
    for (int i = 0; i < 2; ++i) { acc1[i][0] = (f32x4)0.0f; acc1[i][1] = (f32x4)0.0f; }

    // ---- GEMM1: X(64x384) @ w1a, K in 3 segments of 128 ----
#pragma unroll
    for (int s = 0; s < 3; ++s) {
        // stage segment: 64x128 f32 -> bf16 hi/lo, swizzled (4 float4/thread)
#pragma unroll
        for (int it = 0; it < 4; ++it) {
            int q = it * 512 + tid;
            int row = q >> 5, c4 = (q & 31) * 4;
            int t = t0 + row; int tc = (t < T) ? t : (T - 1);
            const float* src = (s == 0) ? obj   + (size_t)sIdx[row] * 128 + c4
                             : (s == 1) ? predi + (size_t)tc        * 128 + c4
                                        : obj   + (size_t)oIdx[row] * 128 + c4;
            float4 v = *(const float4*)src;
            u16x4 hv, lv;
            unsigned short h;
            h = f2bf(v.x); hv[0] = h; lv[0] = f2bf(v.x - bf2f(h));
            h = f2bf(v.y); hv[1] = h; lv[1] = f2bf(v.y - bf2f(h));
            h = f2bf(v.z); hv[2] = h; lv[2] = f2bf(v.z - bf2f(h));
            h = f2bf(v.w); hv[3] = h; lv[3] = f2bf(v.w - bf2f(h));
            int pc = row * 128 + (c4 ^ ((row & 7) << 3));
            *(u16x4*)&Xh[pc] = hv;
            *(u16x4*)&Xl[pc] = lv;
        }
        __syncthreads();

#pragma unroll
        for (int kc2 = 0; kc2 < 4; ++kc2) {
            const int kcg = s * 4 + kc2;
            bf16x8 ah[2], al[2];
#pragma unroll
            for (int rt = 0; rt < 2; ++rt) {
                int row = (rh * 2 + rt) * 16 + (l & 15);
                int col0 = kc2 * 32 + (l >> 4) * 8;
                int pc = row * 128 + (col0 ^ ((row & 7) << 3));
                ah[rt] = *(const bf16x8*)&Xh[pc];
                al[rt] = *(const bf16x8*)&Xl[pc];
            }
#pragma unroll
            for (int c2 = 0; c2 < 2; ++c2) {
                const int tile = kcg * 8 + cg * 2 + c2;
                bf16x8 bh = *(const bf16x8*)&pk1a_h[(size_t)(tile * 64 + l) * 8];
                bf16x8 bl = *(const bf16x8*)&pk1a_l[(size_t)(tile * 64 + l) * 8];
#pragma unroll
                for (int rt = 0; rt < 2; ++rt) {
                    acc1[rt][c2] = MFMA(ah[rt], bh, acc1[rt][c2], 0, 0, 0);
                    acc1[rt][c2] = MFMA(ah[rt], bl, acc1[rt][c2], 0, 0, 0);
                    acc1[rt][c2] = MFMA(al[rt], bh, acc1[rt][c2], 0, 0, 0);
                }
            }
        }
        __syncthreads();   // before next segment restages Xh/Xl
    }

    // ---- H = relu(acc1 + b1a) -> Xh/Xl (hi/lo, swizzled) ----
#pragma unroll
    for (int c2 = 0; c2 < 2; ++c2) {
        int col = cg * 32 + c2 * 16 + (l & 15);
        float bb = b1a[col];
#pragma unroll
        for (int rt = 0; rt < 2; ++rt) {
#pragma unroll
            for (int r = 0; r < 4; ++r) {
                int row = (rh * 2 + rt) * 16 + (l >> 4) * 4 + r;
                float h = fmaxf(acc1[rt][c2][r] + bb, 0.0f);
                unsigned short hh = f2bf(h);
                unsigned short hl = f2bf(h - bf2f(hh));
                int pc = row * 128 + (col ^ ((row & 7) << 3));
                Xh[pc] = hh; Xl[pc] = hl;
            }
        }
    }
    __syncthreads();

    // ---- GEMM2: H(64x128) @ w1b(128x384) ----
    f32x4 acc2[2][6];
#pragma unroll
    for (int i = 0; i < 2; ++i)
#pragma unroll
        for (int j = 0; j < 6; ++j) acc2[i][j] = (f32x4)0.0f;

#pragma unroll
    for (int kc = 0; kc < 4; ++kc) {
        bf16x8 ah[2], al[2];
#pragma unroll
        for (int rt = 0; rt < 2; ++rt) {
            int row = (rh * 2 + rt) * 16 + (l & 15);
            int col0 = kc * 32 + (l >> 4) * 8;
            int pc = row * 128 + (col0 ^ ((row & 7) << 3));
            ah[rt] = *(const bf16x8*)&Xh[pc];
            al[rt] = *(const bf16x8*)&Xl[pc];
        }
#pragma unroll
        for (int ct = 0; ct < 6; ++ct) {
            const int tile = kc * 24 + cg * 6 + ct;
            bf16x8 bh = *(const bf16x8*)&pk1b_h[(size_t)(tile * 64 + l) * 8];
            bf16x8 bl = *(const bf16x8*)&pk1b_l[(size_t)(tile * 64 + l) * 8];
#pragma unroll
            for (int rt = 0; rt < 2; ++rt) {
                acc2[rt][ct] = MFMA(ah[rt], bh, acc2[rt][ct], 0, 0, 0);
                acc2[rt][ct] = MFMA(ah[rt], bl, acc2[rt][ct], 0, 0, 0);
                acc2[rt][ct] = MFMA(al[rt], bh, acc2[rt][ct], 0, 0, 0);
            }
        }
    }

    // ---- epilogue: relu(+b1b); cols 0-127 -> scatter s, 128-255 -> new_p, 256-383 -> scatter o
#pragma unroll
    for (int ct = 0; ct < 6; ++ct) {
        int col = cg * 96 + ct * 16 + (l & 15);
        float bb = b1b[col];
#pragma unroll
        for (int rt = 0; rt < 2; ++rt) {
#pragma unroll
            for (int r = 0; r < 4; ++r) {
                int row = (rh * 2 + rt) * 16 + (l >> 4) * 4 + r;
                if (t0 + row >= T) continue;
                float v = fmaxf(acc2[rt][ct][r] + bb, 0.0f);
                if (col < 128)
                    atomicAdd(&pooled[(size_t)sIdx[row] * 128 + col], v);
                else if (col < 256)
                    out_p[(size_t)(t0 + row) * 128 + (col - 128)] = v;
                else
                    atomicAdd(&pooled[(size_t)oIdx[row] * 128 + (col - 256)], v);
            }
        }
    }
}

// ---------------------------------------------------------------------------
// Kernel C: object MLP with MFMA, 512 thr = 8 waves, 64 rows/block.
// Wave w: rows 32(w&1).., cols 32(w>>1).. for both GEMMs. In-place io.
// ---------------------------------------------------------------------------
__global__ __launch_bounds__(512, 4) void obj_mlp_mfma(
    const float* __restrict__ b2a, const float* __restrict__ b2b,
    const unsigned short* __restrict__ pk2a_h, const unsigned short* __restrict__ pk2a_l,
    const unsigned short* __restrict__ pk2b_h, const unsigned short* __restrict__ pk2b_l,
    float* __restrict__ io, const float* __restrict__ counts, int O)
{
    __shared__ __align__(16) unsigned short Xh[64 * 128];
    __shared__ __align__(16) unsigned short Xl[64 * 128];

    const int tid = threadIdx.x;
    const int w = tid >> 6, l = tid & 63;
    const int rh = w & 1, cg = w >> 1;
    const int r0 = blockIdx.x * 64;

    // stage pooled/counts -> normalized x, bf16 hi/lo swizzled
#pragma unroll
    for (int it = 0; it < 4; ++it) {
        int q = it * 512 + tid;
        int row = q >> 5, c4 = (q & 31) * 4;
        int rg = r0 + row; if (rg > O - 1) rg = O - 1;
        float c = counts[rg];
        c = fminf(fmaxf(c, 1.0f), 1000.0f);
        float inv = 1.0f / c;
        float4 v = *(const float4*)&io[(size_t)rg * 128 + c4];
        v.x *= inv; v.y *= inv; v.z *= inv; v.w *= inv;
        u16x4 hv, lv;
        unsigned short h;
        h = f2bf(v.x); hv[0] = h; lv[0] = f2bf(v.x - bf2f(h));
        h = f2bf(v.y); hv[1] = h; lv[1] = f2bf(v.y - bf2f(h));
        h = f2bf(v.z); hv[2] = h; lv[2] = f2bf(v.z - bf2f(h));
        h = f2bf(v.w); hv[3] = h; lv[3] = f2bf(v.w - bf2f(h));
        int pc = row * 128 + (c4 ^ ((row & 7) << 3));
        *(u16x4*)&Xh[pc] = hv;
        *(u16x4*)&Xl[pc] = lv;
    }
    __syncthreads();

    f32x4 acc[2][2];
#pragma unroll
    for (int i = 0; i < 2; ++i) { acc[i][0] = (f32x4)0.0f; acc[i][1] = (f32x4)0.0f; }

    // GEMM1: x @ w2a (128x128)
#pragma unroll
    for (int kc = 0; kc < 4; ++kc) {
        bf16x8 ah[2], al[2];
#pragma unroll
        for (int rt = 0; rt < 2; ++rt) {
            int row = (rh * 2 + rt) * 16 + (l & 15);
            int col0 = kc * 32 + (l >> 4) * 8;
            int pc = row * 128 + (col0 ^ ((row & 7) << 3));
            ah[rt] = *(const bf16x8*)&Xh[pc];
            al[rt] = *(const bf16x8*)&Xl[pc];
        }
#pragma unroll
        for (int c2 = 0; c2 < 2; ++c2) {
            const int tile = kc * 8 + cg * 2 + c2;
            bf16x8 bh = *(const bf16x8*)&pk2a_h[(size_t)(tile * 64 + l) * 8];
            bf16x8 bl = *(const bf16x8*)&pk2a_l[(size_t)(tile * 64 + l) * 8];
#pragma unroll
            for (int rt = 0; rt < 2; ++rt) {
                acc[rt][c2] = MFMA(ah[rt], bh, acc[rt][c2], 0, 0, 0);
                acc[rt][c2] = MFMA(ah[rt], bl, acc[rt][c2], 0, 0, 0);
                acc[rt][c2] = MFMA(al[rt], bh, acc[rt][c2], 0, 0, 0);
            }
        }
    }
    __syncthreads();   // all GEMM1 reads done before H overwrite

    // H = relu(acc + b2a) -> Xh/Xl
#pragma unroll
    for (int c2 = 0; c2 < 2; ++c2) {
        int col = cg * 32 + c2 * 16 + (l & 15);
        float bb = b2a[col];
#pragma unroll
        for (int rt = 0; rt < 2; ++rt) {
#pragma unroll
            for (int r = 0; r < 4; ++r) {
                int row = (rh * 2 + rt) * 16 + (l >> 4) * 4 + r;
                float h = fmaxf(acc[rt][c2][r] + bb, 0.0f);
                unsigned short hh = f2bf(h);
                unsigned short hl = f2bf(h - bf2f(hh));
                int pc = row * 128 + (col ^ ((row & 7) << 3));
                Xh[pc] = hh; Xl[pc] = hl;
            }
        }
    }
    __syncthreads();

    f32x4 acc2[2][2];
#pragma unroll
    for (int i = 0; i < 2; ++i) { acc2[i][0] = (f32x4)0.0f; acc2[i][1] = (f32x4)0.0f; }

    // GEMM2: h @ w2b (128x128)
#pragma unroll
    for (int kc = 0; kc < 4; ++kc) {
        bf16x8 ah[2], al[2];
#pragma unroll
        for (int rt = 0; rt < 2; ++rt) {
            int row = (rh * 2 + rt) * 16 + (l & 15);
            int col0 = kc * 32 + (l >> 4) * 8;
            int pc = row * 128 + (col0 ^ ((row & 7) << 3));
            ah[rt] = *(const bf16x8*)&Xh[pc];
            al[rt] = *(const bf16x8*)&Xl[pc];
        }
#pragma unroll
        for (int c2 = 0; c2 < 2; ++c2) {
            const int tile = kc * 8 + cg * 2 + c2;
            bf16x8 bh = *(const bf16x8*)&pk2b_h[(size_t)(tile * 64 + l) * 8];
            bf16x8 bl = *(const bf16x8*)&pk2b_l[(size_t)(tile * 64 + l) * 8];
#pragma unroll
            for (int rt = 0; rt < 2; ++rt) {
                acc2[rt][c2] = MFMA(ah[rt], bh, acc2[rt][c2], 0, 0, 0);
                acc2[rt][c2] = MFMA(ah[rt], bl, acc2[rt][c2], 0, 0, 0);
                acc2[rt][c2] = MFMA(al[rt], bh, acc2[rt][c2], 0, 0, 0);
            }
        }
    }

    // epilogue: new_obj = relu(acc2 + b2b), in-place store
#pragma unroll
    for (int c2 = 0; c2 < 2; ++c2) {
        int col = cg * 32 + c2 * 16 + (l & 15);
        float bb = b2b[col];
#pragma unroll
        for (int rt = 0; rt < 2; ++rt) {
#pragma unroll
            for (int r = 0; r < 4; ++r) {
                int row = (rh * 2 + rt) * 16 + (l >> 4) * 4 + r;
                if (r0 + row >= O) continue;
                float v = fmaxf(acc2[rt][c2][r] + bb, 0.0f);
                io[(size_t)(r0 + row) * 128 + col] = v;
            }
        }
    }
}

extern "C" void kernel_launch(void* const* d_in, const int* in_sizes, int n_in,
                              void* d_out, int out_size, void* d_ws, size_t ws_size,
                              hipStream_t stream) {
    const float* obj   = (const float*)d_in[0];
    const float* predi = (const float*)d_in[1];
    const int*   edges = (const int*)d_in[2];
    const float* w1a   = (const float*)d_in[3];
    const float* b1a   = (const float*)d_in[4];
    const float* w1b   = (const float*)d_in[5];
    const float* b1b   = (const float*)d_in[6];
    const float* w2a   = (const float*)d_in[7];
    const float* b2a   = (const float*)d_in[8];
    const float* w2b   = (const float*)d_in[9];
    const float* b2b   = (const float*)d_in[10];
    (void)n_in; (void)ws_size; (void)out_size;

    const int O = in_sizes[0] / 128;
    const int T = in_sizes[1] / 128;

    float* out    = (float*)d_out;
    float* pooled = out;                        // new_obj region doubles as pooled scratch
    float* out_p  = out + (size_t)O * 128;      // new_p region
    float* counts = (float*)d_ws;               // O floats

    unsigned short* pk = (unsigned short*)(counts + O);
    unsigned short* pk1a_h = pk;
    unsigned short* pk1a_l = pk1a_h + 96 * 512;
    unsigned short* pk1b_h = pk1a_l + 96 * 512;
    unsigned short* pk1b_l = pk1b_h + 96 * 512;
    unsigned short* pk2a_h = pk1b_l + 96 * 512;
    unsigned short* pk2a_l = pk2a_h + 32 * 512;
    unsigned short* pk2b_h = pk2a_l + 32 * 512;
    unsigned short* pk2b_l = pk2b_h + 32 * 512;

    hipMemsetAsync(pooled, 0, (size_t)O * 128 * sizeof(float), stream);
    hipMemsetAsync(counts, 0, (size_t)O * sizeof(float), stream);

    pack_weights<<<256, 64, 0, stream>>>(w1a, w1b, w2a, w2b, pk);

    triple_mlp_mfma<<<(T + 63) / 64, 512, 0, stream>>>(
        obj, predi, edges, b1a, b1b,
        pk1a_h, pk1a_l, pk1b_h, pk1b_l,
        pooled, out_p, counts, T);

    obj_mlp_mfma<<<(O + 63) / 64, 512, 0, stream>>>(
        b2a, b2b, pk2a_h, pk2a_l, pk2b_h, pk2b_l,
        pooled, counts, O);
}